// Round 1
// baseline (171.124 us; speedup 1.0000x reference)
//
#include <hip/hip_runtime.h>

#define C_DIM 1000
#define CV    250   // C_DIM / 4

// ---------------------------------------------------------------------------
// Kernel 1: per-column partial reductions.
// Thread t (< 250) owns columns [4t, 4t+4). Each block grid-strides over rows.
// Accumulate in registers, then one atomicAdd per column per accumulator.
// Row base = r*1000 floats = 4000 B -> 16B-aligned, so float4/int4 loads are legal.
// ---------------------------------------------------------------------------
__global__ __launch_bounds__(256) void nrl_partial_kernel(
    const float* __restrict__ pred,
    const int*   __restrict__ labels,
    float*        __restrict__ ws_sp_pos,
    float*        __restrict__ ws_sp_neg,
    unsigned int* __restrict__ ws_cnt,
    int N)
{
    const int t = threadIdx.x;
    if (t >= CV) return;
    const int c0 = t * 4;

    float sp_pos[4] = {0.f, 0.f, 0.f, 0.f};
    float sp_neg[4] = {0.f, 0.f, 0.f, 0.f};
    unsigned int cnt[4] = {0u, 0u, 0u, 0u};   // n_pos | (n_neg << 16)

    for (int r = blockIdx.x; r < N; r += gridDim.x) {
        const size_t base = (size_t)r * C_DIM + c0;
        const float4 p = *reinterpret_cast<const float4*>(pred + base);
        const int4   y = *reinterpret_cast<const int4*>(labels + base);

        const float px[4] = {p.x, p.y, p.z, p.w};
        const int   yy[4] = {y.x, y.y, y.z, y.w};

#pragma unroll
        for (int j = 0; j < 4; ++j) {
            const float x  = px[j];
            // shared stable-softplus core: log1p(exp(-|x|))
            const float tl = log1pf(__expf(-fabsf(x)));
            const float lp = tl + fmaxf(-x, 0.f);   // softplus(-x)
            const float ln = tl + fmaxf( x, 0.f);   // softplus( x)
            const bool isp = (yy[j] == 1);
            const bool isn = (yy[j] == 0);
            sp_pos[j] += isp ? lp : 0.f;
            sp_neg[j] += isn ? ln : 0.f;
            cnt[j]    += (isp ? 1u : 0u) + (isn ? 0x10000u : 0u);
        }
    }

#pragma unroll
    for (int j = 0; j < 4; ++j) {
        atomicAdd(&ws_sp_pos[c0 + j], sp_pos[j]);
        atomicAdd(&ws_sp_neg[c0 + j], sp_neg[j]);
        atomicAdd(&ws_cnt[c0 + j],    cnt[j]);
    }
}

// ---------------------------------------------------------------------------
// Kernel 2: per-class loss + masked mean over valid classes. One block.
// ---------------------------------------------------------------------------
__global__ __launch_bounds__(1024) void nrl_finalize_kernel(
    const float*        __restrict__ ws_sp_pos,
    const float*        __restrict__ ws_sp_neg,
    const unsigned int* __restrict__ ws_cnt,
    float* __restrict__ out)
{
    const int t = threadIdx.x;
    float loss   = 0.f;
    float validf = 0.f;
    if (t < C_DIM) {
        const unsigned int c = ws_cnt[t];
        const float np = (float)(c & 0xFFFFu);
        const float nn = (float)(c >> 16);
        const bool valid = (np > 0.f) && (nn > 0.f);
        const float l = ws_sp_pos[t] / fmaxf(np, 1.f)
                      + ws_sp_neg[t] / fmaxf(nn, 1.f);
        loss   = valid ? l   : 0.f;
        validf = valid ? 1.f : 0.f;
    }

    // wave (64-lane) shuffle reduce
#pragma unroll
    for (int off = 32; off > 0; off >>= 1) {
        loss   += __shfl_down(loss,   off);
        validf += __shfl_down(validf, off);
    }

    __shared__ float s_l[16];
    __shared__ float s_v[16];
    const int wid  = t >> 6;
    const int lane = t & 63;
    if (lane == 0) { s_l[wid] = loss; s_v[wid] = validf; }
    __syncthreads();

    if (t == 0) {
        float L = 0.f, V = 0.f;
#pragma unroll
        for (int i = 0; i < 16; ++i) { L += s_l[i]; V += s_v[i]; }
        out[0] = L / fmaxf(V, 1.f);
    }
}

// ---------------------------------------------------------------------------
extern "C" void kernel_launch(void* const* d_in, const int* in_sizes, int n_in,
                              void* d_out, int out_size, void* d_ws, size_t ws_size,
                              hipStream_t stream)
{
    const float* pred   = (const float*)d_in[0];
    const int*   labels = (const int*)d_in[1];
    const int N = in_sizes[0] / C_DIM;

    float*        ws_sp_pos = (float*)d_ws;
    float*        ws_sp_neg = ws_sp_pos + 1024;
    unsigned int* ws_cnt    = (unsigned int*)(ws_sp_neg + 1024);

    // zero the 12 KB of accumulators (capturable async memset)
    hipMemsetAsync(d_ws, 0, 3 * 1024 * sizeof(float), stream);

    const int nblocks = 1024;   // 4 blocks/CU, 16 waves/CU; 32 rows per block
    nrl_partial_kernel<<<nblocks, 256, 0, stream>>>(pred, labels,
                                                    ws_sp_pos, ws_sp_neg, ws_cnt, N);
    nrl_finalize_kernel<<<1, 1024, 0, stream>>>(ws_sp_pos, ws_sp_neg, ws_cnt,
                                                (float*)d_out);
}